// Round 1
// baseline (631.842 us; speedup 1.0000x reference)
//
#include <hip/hip_runtime.h>

#define DD 128
#define GG 500
#define NSTK 100
#define SLOPE 0.2f
#define BN_EPS 1e-5f

// ---------------- CSR build ----------------

__global__ __launch_bounds__(256) void hist_kernel(const int* __restrict__ dst,
                                                   int* __restrict__ deg, int e_count) {
    int e = blockIdx.x * 256 + threadIdx.x;
    if (e < e_count) atomicAdd(&deg[dst[e]], 1);
}

// per-wave exclusive scan + one atomic per wave (avoids 50k serialized atomics on one counter)
__global__ __launch_bounds__(256) void offsets_kernel(const int* __restrict__ deg,
                                                      int* __restrict__ start,
                                                      int* __restrict__ cursor,
                                                      int* __restrict__ total, int n) {
    int i = blockIdx.x * 256 + threadIdx.x;
    int lane = threadIdx.x & 63;
    int d = (i < n) ? deg[i] : 0;
    int pre = d;
    #pragma unroll
    for (int off = 1; off < 64; off <<= 1) {
        int t = __shfl_up(pre, off, 64);
        if (lane >= off) pre += t;
    }
    int wavesum = __shfl(pre, 63, 64);
    int base = 0;
    if (lane == 0) base = atomicAdd(total, wavesum);
    base = __shfl(base, 0, 64);
    if (i < n) {
        int s0 = base + pre - d;   // exclusive prefix within wave + global base
        start[i] = s0;
        cursor[i] = s0;
    }
}

__global__ __launch_bounds__(256) void scatter_kernel(const int* __restrict__ src,
                                                      const int* __restrict__ dst,
                                                      int* __restrict__ cursor,
                                                      int* __restrict__ csr_src, int e_count) {
    int e = blockIdx.x * 256 + threadIdx.x;
    if (e < e_count) {
        int d = dst[e];
        int p = atomicAdd(&cursor[d], 1);
        csr_src[p] = src[e];
    }
}

__global__ void bn_prep_kernel(const float* __restrict__ g, const float* __restrict__ b,
                               const float* __restrict__ m, const float* __restrict__ v,
                               float* __restrict__ scale, float* __restrict__ shift) {
    int i = threadIdx.x;
    float s = g[i] * rsqrtf(v[i] + BN_EPS);
    scale[i] = s;
    shift[i] = b[i] - m[i] * s;
}

// ---------------- dual matmul: outA = x@wA + bA ; outB = x@wB + bB ----------------
// 32 rows x 128 cols per block; w staged in 64-row halves (48 KB LDS -> 3 blocks/CU)

__global__ __launch_bounds__(256) void dualmm_kernel(
    const float* __restrict__ x,
    const float* __restrict__ wA, const float* __restrict__ bA, float* __restrict__ outA,
    const float* __restrict__ wB, const float* __restrict__ bB, float* __restrict__ outB,
    int n)
{
    __shared__ float xs[32][DD];     // 16 KB
    __shared__ float wsh[64][DD];    // 32 KB
    int t = threadIdx.x;
    int row0 = blockIdx.x * 32;

    #pragma unroll
    for (int i = 0; i < 4; ++i) {
        int idx = (i * 256 + t) * 4;        // 0..4095
        int r = idx >> 7, c = idx & 127;
        float4 v = make_float4(0.f, 0.f, 0.f, 0.f);
        if (row0 + r < n) v = *(const float4*)&x[(size_t)(row0 + r) * DD + c];
        *(float4*)&xs[r][c] = v;
    }

    int col = (t & 31) * 4;        // output col base
    int rbase = (t >> 5) * 4;      // output row base within tile

    const float* wmat[2] = {wA, wB};
    const float* bvec[2] = {bA, bB};
    float* omat[2] = {outA, outB};

    for (int side = 0; side < 2; ++side) {
        float acc[4][4];
        #pragma unroll
        for (int m = 0; m < 4; ++m)
            #pragma unroll
            for (int c = 0; c < 4; ++c) acc[m][c] = 0.f;
        const float* w = wmat[side];
        for (int half = 0; half < 2; ++half) {
            __syncthreads();
            #pragma unroll
            for (int i = 0; i < 8; ++i) {
                int idx = (i * 256 + t) * 4;   // 0..8191
                int r = idx >> 7, c = idx & 127;
                *(float4*)&wsh[r][c] = *(const float4*)&w[(size_t)(half * 64 + r) * DD + c];
            }
            __syncthreads();
            #pragma unroll
            for (int k4 = 0; k4 < 16; ++k4) {
                int kb = half * 64 + k4 * 4;
                float xq[4][4];
                #pragma unroll
                for (int m = 0; m < 4; ++m)
                    *(float4*)&xq[m][0] = *(const float4*)&xs[rbase + m][kb];
                #pragma unroll
                for (int kk = 0; kk < 4; ++kk) {
                    float4 wv = *(const float4*)&wsh[k4 * 4 + kk][col];
                    #pragma unroll
                    for (int m = 0; m < 4; ++m) {
                        float a = xq[m][kk];
                        acc[m][0] += a * wv.x;
                        acc[m][1] += a * wv.y;
                        acc[m][2] += a * wv.z;
                        acc[m][3] += a * wv.w;
                    }
                }
            }
        }
        float4 bb = *(const float4*)&bvec[side][col];
        #pragma unroll
        for (int m = 0; m < 4; ++m) {
            int r = row0 + rbase + m;
            if (r < n) {
                float4 o;
                o.x = acc[m][0] + bb.x; o.y = acc[m][1] + bb.y;
                o.z = acc[m][2] + bb.z; o.w = acc[m][3] + bb.w;
                *(float4*)&omat[side][(size_t)r * DD + col] = o;
            }
        }
    }
}

// ---------------- fused GATv2 edge phase: one wave per dst node ----------------
// e = att . lrelu(xl[src] + xr[dst]); p = exp(e)  (softmax shift-invariant; logits ~O(1))
// out[dst] = (sum p * xl[src]) / (sum p) + b  [then optional BN+ReLU]

__global__ __launch_bounds__(256) void gat_agg_kernel(
    const float* __restrict__ xl, const float* __restrict__ xr,
    const int* __restrict__ row_start, const int* __restrict__ degv,
    const int* __restrict__ csr_src,
    const float* __restrict__ att, const float* __restrict__ bias,
    const float* __restrict__ bn_scale, const float* __restrict__ bn_shift,
    float* __restrict__ out, int n, int use_bn)
{
    int wave = (int)((blockIdx.x * 256 + threadIdx.x) >> 6);
    int lane = threadIdx.x & 63;
    if (wave >= n) return;
    int nstart = row_start[wave];
    int deg = degv[wave];
    int f = lane * 2;

    float2 xrv = *(const float2*)&xr[(size_t)wave * DD + f];
    float2 attv = *(const float2*)&att[f];

    float acc0 = 0.f, acc1 = 0.f, den = 0.f;
    for (int j = 0; j < deg; ++j) {
        int s = csr_src[nstart + j];
        float2 a = *(const float2*)&xl[(size_t)s * DD + f];
        float t0 = a.x + xrv.x;
        float t1 = a.y + xrv.y;
        t0 = t0 > 0.f ? t0 : SLOPE * t0;
        t1 = t1 > 0.f ? t1 : SLOPE * t1;
        float partial = attv.x * t0 + attv.y * t1;
        #pragma unroll
        for (int off = 32; off; off >>= 1) partial += __shfl_xor(partial, off, 64);
        float p = __expf(partial);
        den += p;
        acc0 += p * a.x;
        acc1 += p * a.y;
    }
    float inv = (deg > 0) ? 1.0f / den : 0.0f;
    float o0 = acc0 * inv + bias[f];
    float o1 = acc1 * inv + bias[f + 1];
    if (use_bn) {
        o0 = o0 * bn_scale[f] + bn_shift[f];
        o1 = o1 * bn_scale[f + 1] + bn_shift[f + 1];
        o0 = o0 > 0.f ? o0 : 0.f;
        o1 = o1 > 0.f ? o1 : 0.f;
    }
    *(float2*)&out[(size_t)wave * DD + f] = make_float2(o0, o1);
}

// ---------------- global mean pool (batch sorted -> binary search boundaries) ----------------

__device__ __forceinline__ int lower_bound_dev(const int* __restrict__ arr, int n, int val) {
    int lo = 0, hi = n;
    while (lo < hi) {
        int mid = (lo + hi) >> 1;
        if (arr[mid] < val) lo = mid + 1; else hi = mid;
    }
    return lo;
}

__global__ __launch_bounds__(128) void pool_kernel(const float* __restrict__ h,
                                                   const int* __restrict__ batch,
                                                   float* __restrict__ pooled, int n) {
    int g = blockIdx.x;
    int f = threadIdx.x;
    int lo = lower_bound_dev(batch, n, g);
    int hi = lower_bound_dev(batch, n, g + 1);
    float s = 0.f;
    for (int i = lo; i < hi; ++i) s += h[(size_t)i * DD + f];
    float cnt = (float)(hi - lo);
    pooled[(size_t)g * DD + f] = s / fmaxf(cnt, 1.0f);
}

// ---------------- fused head: sigmoid(relu(pooled@fc1_w + fc1_b) @ fc3_w + fc3_b) ----------------
// one wave per (stock, 20-graph chunk); lane j holds fc1_w column s*64+j in registers

__global__ __launch_bounds__(64) void head_kernel(
    const float* __restrict__ pooled, const float* __restrict__ fc1_w,
    const float* __restrict__ fc1_b, const float* __restrict__ fc3_w,
    const float* __restrict__ fc3_b, float* __restrict__ out)
{
    int sIdx = blockIdx.x;      // 0..99
    int gbase = blockIdx.y * 20;
    int j = threadIdx.x;        // 0..63

    float wreg[DD];
    #pragma unroll
    for (int k = 0; k < DD; ++k)
        wreg[k] = fc1_w[(size_t)k * (NSTK * 64) + sIdx * 64 + j];
    float b1 = fc1_b[sIdx * 64 + j];
    float w3 = fc3_w[j];
    float b3 = fc3_b[0];

    for (int gi = 0; gi < 20; ++gi) {
        int g = gbase + gi;
        float acc = b1;
        #pragma unroll
        for (int k4 = 0; k4 < DD / 4; ++k4) {
            float4 pv = *(const float4*)&pooled[(size_t)g * DD + k4 * 4];
            acc += pv.x * wreg[k4 * 4 + 0];
            acc += pv.y * wreg[k4 * 4 + 1];
            acc += pv.z * wreg[k4 * 4 + 2];
            acc += pv.w * wreg[k4 * 4 + 3];
        }
        float r = acc > 0.f ? acc : 0.f;
        float v = r * w3;
        #pragma unroll
        for (int off = 32; off; off >>= 1) v += __shfl_xor(v, off, 64);
        if (j == 0) out[(size_t)g * NSTK + sIdx] = 1.0f / (1.0f + __expf(-(v + b3)));
    }
}

// ---------------- launch ----------------

extern "C" void kernel_launch(void* const* d_in, const int* in_sizes, int n_in,
                              void* d_out, int out_size, void* d_ws, size_t ws_size,
                              hipStream_t stream) {
    const float* x        = (const float*)d_in[0];
    const int*   graph    = (const int*)d_in[1];
    const int*   batch    = (const int*)d_in[2];
    const float* wl0      = (const float*)d_in[3];
    const float* bl0      = (const float*)d_in[4];
    const float* wr0      = (const float*)d_in[5];
    const float* br0      = (const float*)d_in[6];
    const float* att0     = (const float*)d_in[7];
    const float* b0       = (const float*)d_in[8];
    const float* wl1      = (const float*)d_in[9];
    const float* bl1      = (const float*)d_in[10];
    const float* wr1      = (const float*)d_in[11];
    const float* br1      = (const float*)d_in[12];
    const float* att1     = (const float*)d_in[13];
    const float* b1       = (const float*)d_in[14];
    const float* bn_gamma = (const float*)d_in[15];
    const float* bn_beta  = (const float*)d_in[16];
    const float* bn_mean  = (const float*)d_in[17];
    const float* bn_var   = (const float*)d_in[18];
    const float* fc1_w    = (const float*)d_in[19];
    const float* fc1_b    = (const float*)d_in[20];
    const float* fc3_w    = (const float*)d_in[21];
    const float* fc3_b    = (const float*)d_in[22];
    float* out = (float*)d_out;

    int n       = in_sizes[0] / DD;   // 50000
    int e_count = in_sizes[1] / 2;    // 800000
    const int* srcv = graph;
    const int* dstv = graph + e_count;

    // workspace layout (floats then ints), ~81 MB total
    float* A        = (float*)d_ws;                 // xl   [n*DD]
    float* B        = A + (size_t)n * DD;           // xr   [n*DD]
    float* C        = B + (size_t)n * DD;           // h    [n*DD]
    float* pooled   = C + (size_t)n * DD;           // [GG*DD]
    float* bn_scale = pooled + (size_t)GG * DD;     // [DD]
    float* bn_shift = bn_scale + DD;                // [DD]
    int* deg     = (int*)(bn_shift + DD);           // [n]
    int* total   = deg + n;                         // [1]
    int* start   = total + 1;                       // [n]
    int* cursor  = start + n;                       // [n]
    int* csr_src = cursor + n;                      // [e_count]

    // CSR build (same graph both layers)
    hipMemsetAsync(deg, 0, (size_t)(n + 1) * sizeof(int), stream);   // deg + total
    hist_kernel<<<(e_count + 255) / 256, 256, 0, stream>>>(dstv, deg, e_count);
    offsets_kernel<<<(n + 255) / 256, 256, 0, stream>>>(deg, start, cursor, total, n);
    scatter_kernel<<<(e_count + 255) / 256, 256, 0, stream>>>(srcv, dstv, cursor, csr_src, e_count);
    bn_prep_kernel<<<1, DD, 0, stream>>>(bn_gamma, bn_beta, bn_mean, bn_var, bn_scale, bn_shift);

    int mmblocks = (n + 31) / 32;
    int aggblocks = (n + 3) / 4;

    // layer 0: dual matmul -> fused edge softmax/aggregate + BN + ReLU
    dualmm_kernel<<<mmblocks, 256, 0, stream>>>(x, wl0, bl0, A, wr0, br0, B, n);
    gat_agg_kernel<<<aggblocks, 256, 0, stream>>>(A, B, start, deg, csr_src, att0, b0,
                                                  bn_scale, bn_shift, C, n, 1);
    // layer 1
    dualmm_kernel<<<mmblocks, 256, 0, stream>>>(C, wl1, bl1, A, wr1, br1, B, n);
    gat_agg_kernel<<<aggblocks, 256, 0, stream>>>(A, B, start, deg, csr_src, att1, b1,
                                                  nullptr, nullptr, C, n, 0);
    // pool + head
    pool_kernel<<<GG, DD, 0, stream>>>(C, batch, pooled, n);
    head_kernel<<<dim3(NSTK, GG / 20), 64, 0, stream>>>(pooled, fc1_w, fc1_b, fc3_w, fc3_b, out);
}